// Round 2
// baseline (95.355 us; speedup 1.0000x reference)
//
#include <hip/hip_runtime.h>
#include <hip/hip_bf16.h>
#include <hip/hip_cooperative_groups.h>

namespace cg = cooperative_groups;

// EdgePrompt: out[e] = edge_weight[e] * sigmoid( x[src[e]]·W[:d] + x[dst[e]]·W[d:] + b )
// Fused single cooperative kernel:
//   phase 1: proj_src[n] = x[n]·W[:d], proj_dst[n] = x[n]·W[d:]  (into d_ws)
//   grid.sync()
//   phase 2: per-edge gather + sigmoid + scale, 4 edges/thread vectorized.

#define IN_DIM 128
#define GRID_BLOCKS 1024   // 4 blocks/CU on 256 CUs — trivially co-resident
#define BLOCK 256

__global__ void __launch_bounds__(BLOCK)
edgeprompt_fused(const float* __restrict__ x,
                 const int* __restrict__ edge_index,   // [2*E]: [0,E)=src, [E,2E)=dst
                 const float* __restrict__ edge_weight,
                 const float* __restrict__ W,          // [2*IN_DIM]
                 const float* __restrict__ bias_p,
                 float* __restrict__ out,
                 float* __restrict__ proj,             // d_ws: [2*n_nodes]
                 int n_nodes, int n_edges) {
    const int tid = blockIdx.x * blockDim.x + threadIdx.x;
    const int nthreads = gridDim.x * blockDim.x;
    const int lane = threadIdx.x & 63;
    const int half = lane >> 5;        // which node of the wave's pair
    const int sl = lane & 31;          // sub-lane within the 32-lane group
    const int wave = tid >> 6;
    const int nwaves = nthreads >> 6;

    // ---- Phase 1: node projections. 2 nodes/wave, float4 (16 B/lane). ----
    // W is 1 KB, node-invariant: hoist per-lane fragments.
    const float4 ws = *reinterpret_cast<const float4*>(&W[sl * 4]);
    const float4 wd = *reinterpret_cast<const float4*>(&W[IN_DIM + sl * 4]);

    const int npairs = (n_nodes + 1) >> 1;
    for (int p = wave; p < npairs; p += nwaves) {
        const int n = p * 2 + half;
        float ps = 0.f, pd = 0.f;
        if (n < n_nodes) {
            const float4 xv = *reinterpret_cast<const float4*>(&x[(size_t)n * IN_DIM + sl * 4]);
            ps = xv.x * ws.x + xv.y * ws.y + xv.z * ws.z + xv.w * ws.w;
            pd = xv.x * wd.x + xv.y * wd.y + xv.z * wd.z + xv.w * wd.w;
        }
        // 32-lane butterfly (xor masks < 32 never cross the half boundary)
        #pragma unroll
        for (int off = 16; off > 0; off >>= 1) {
            ps += __shfl_xor(ps, off);
            pd += __shfl_xor(pd, off);
        }
        if (sl == 0 && n < n_nodes) {
            proj[n] = ps;
            proj[n_nodes + n] = pd;
        }
    }

    cg::this_grid().sync();

    // ---- Phase 2: edges, 4 per thread. ----
    const float bias = bias_p[0];
    const float* __restrict__ proj_d = proj + n_nodes;
    const int nquads = n_edges >> 2;
    for (int q = tid; q < nquads; q += nthreads) {
        const int4 s4 = *reinterpret_cast<const int4*>(&edge_index[q * 4]);
        const int4 d4 = *reinterpret_cast<const int4*>(&edge_index[n_edges + q * 4]);
        const float4 w4 = *reinterpret_cast<const float4*>(&edge_weight[q * 4]);
        float4 o;
        o.x = w4.x / (1.0f + __expf(-(proj[s4.x] + proj_d[d4.x] + bias)));
        o.y = w4.y / (1.0f + __expf(-(proj[s4.y] + proj_d[d4.y] + bias)));
        o.z = w4.z / (1.0f + __expf(-(proj[s4.z] + proj_d[d4.z] + bias)));
        o.w = w4.w / (1.0f + __expf(-(proj[s4.w] + proj_d[d4.w] + bias)));
        *reinterpret_cast<float4*>(&out[q * 4]) = o;
    }
    // tail (n_edges % 4)
    for (int e = (nquads << 2) + tid; e < n_edges; e += nthreads) {
        const int s = edge_index[e];
        const int d = edge_index[n_edges + e];
        const float sig = 1.0f / (1.0f + __expf(-(proj[s] + proj_d[d] + bias)));
        out[e] = edge_weight[e] * sig;
    }
}

extern "C" void kernel_launch(void* const* d_in, const int* in_sizes, int n_in,
                              void* d_out, int out_size, void* d_ws, size_t ws_size,
                              hipStream_t stream) {
    // setup_inputs() order: x, edge_index, edge_weight, W, b
    const float* x           = (const float*)d_in[0];
    const int*   edge_index  = (const int*)d_in[1];
    const float* edge_weight = (const float*)d_in[2];
    const float* W           = (const float*)d_in[3];
    const float* b           = (const float*)d_in[4];
    float* out = (float*)d_out;

    int n_nodes = in_sizes[0] / IN_DIM;     // 50000
    int n_edges = in_sizes[2];              // 500000
    float* proj = (float*)d_ws;             // 2 * n_nodes floats = 400 KB

    void* args[] = {(void*)&x, (void*)&edge_index, (void*)&edge_weight, (void*)&W,
                    (void*)&b, (void*)&out, (void*)&proj, (void*)&n_nodes, (void*)&n_edges};
    hipLaunchCooperativeKernel((const void*)edgeprompt_fused,
                               dim3(GRID_BLOCKS), dim3(BLOCK), args, 0, stream);
}

// Round 3
// 17.264 us; speedup vs baseline: 5.5234x; 5.5234x over previous
//
#include <hip/hip_runtime.h>
#include <hip/hip_bf16.h>

// EdgePrompt: out[e] = edge_weight[e] * sigmoid( x[src[e]]·W[:d] + x[dst[e]]·W[d:] + b )
// Two launches (graph-captured back-to-back; cooperative grid.sync was a 4.6x
// regression due to cross-XCD spin — see R2 post-mortem):
//   K1: proj_src[n] = x[n]·W[:d], proj_dst[n] = x[n]·W[d:]  (into d_ws)
//   K2: per-edge gather + sigmoid + scale, 4 edges/thread vectorized.

#define IN_DIM 128
#define BLOCK 256

// K1: each 32-lane half-wave owns one node; lane loads float4 (16 B/lane,
// fully coalesced across the wave). 5-level butterfly reduce within the
// 32-group (xor offsets <32 never cross the half boundary).
__global__ void __launch_bounds__(BLOCK)
edgeprompt_proj(const float* __restrict__ x,
                const float* __restrict__ W,
                float* __restrict__ proj,   // [2*n_nodes]: [0,N)=src-proj, [N,2N)=dst-proj
                int n_nodes) {
    const int lane = threadIdx.x & 63;
    const int half = lane >> 5;
    const int sl   = lane & 31;
    const int wave = (blockIdx.x * blockDim.x + threadIdx.x) >> 6;

    // W is 1 KB, node-invariant: hoist per-lane fragments (L1-resident).
    const float4 ws = *reinterpret_cast<const float4*>(&W[sl * 4]);
    const float4 wd = *reinterpret_cast<const float4*>(&W[IN_DIM + sl * 4]);

    const int n = wave * 2 + half;
    if (n >= n_nodes) return;

    const float4 xv = *reinterpret_cast<const float4*>(&x[(size_t)n * IN_DIM + sl * 4]);
    float ps = xv.x * ws.x + xv.y * ws.y + xv.z * ws.z + xv.w * ws.w;
    float pd = xv.x * wd.x + xv.y * wd.y + xv.z * wd.z + xv.w * wd.w;
    #pragma unroll
    for (int off = 16; off > 0; off >>= 1) {
        ps += __shfl_xor(ps, off);
        pd += __shfl_xor(pd, off);
    }
    if (sl == 0) {
        proj[n] = ps;
        proj[n_nodes + n] = pd;
    }
}

// K2: 4 edges/thread, vectorized streaming loads/stores; 8 independent 4B
// gathers/thread into the two 200 KB L2-resident proj tables.
__global__ void __launch_bounds__(BLOCK)
edgeprompt_edges(const int* __restrict__ edge_index,   // [2*E]: [0,E)=src, [E,2E)=dst
                 const float* __restrict__ edge_weight,
                 const float* __restrict__ proj,       // [2*n_nodes]
                 const float* __restrict__ bias_p,
                 float* __restrict__ out,
                 int n_edges, int n_nodes) {
    const int tid = blockIdx.x * blockDim.x + threadIdx.x;
    const float bias = bias_p[0];
    const float* __restrict__ proj_d = proj + n_nodes;

    const int q = tid;                 // quad index
    const int nquads = n_edges >> 2;
    if (q < nquads) {
        const int4   s4 = *reinterpret_cast<const int4*>(&edge_index[q * 4]);
        const int4   d4 = *reinterpret_cast<const int4*>(&edge_index[n_edges + q * 4]);
        const float4 w4 = *reinterpret_cast<const float4*>(&edge_weight[q * 4]);
        float4 o;
        o.x = w4.x / (1.0f + __expf(-(proj[s4.x] + proj_d[d4.x] + bias)));
        o.y = w4.y / (1.0f + __expf(-(proj[s4.y] + proj_d[d4.y] + bias)));
        o.z = w4.z / (1.0f + __expf(-(proj[s4.z] + proj_d[d4.z] + bias)));
        o.w = w4.w / (1.0f + __expf(-(proj[s4.w] + proj_d[d4.w] + bias)));
        *reinterpret_cast<float4*>(&out[q * 4]) = o;
    }
    // tail (n_edges % 4), handled by the first few threads
    const int e = (nquads << 2) + tid;
    if (e < n_edges) {
        const int s = edge_index[e];
        const int d = edge_index[n_edges + e];
        out[e] = edge_weight[e] / (1.0f + __expf(-(proj[s] + proj_d[d] + bias)));
    }
}

extern "C" void kernel_launch(void* const* d_in, const int* in_sizes, int n_in,
                              void* d_out, int out_size, void* d_ws, size_t ws_size,
                              hipStream_t stream) {
    // setup_inputs() order: x, edge_index, edge_weight, W, b
    const float* x           = (const float*)d_in[0];
    const int*   edge_index  = (const int*)d_in[1];
    const float* edge_weight = (const float*)d_in[2];
    const float* W           = (const float*)d_in[3];
    const float* b           = (const float*)d_in[4];
    float* out = (float*)d_out;

    const int n_nodes = in_sizes[0] / IN_DIM;   // 50000
    const int n_edges = in_sizes[2];            // 500000
    float* proj = (float*)d_ws;                 // 2*n_nodes floats = 400 KB

    // K1: 2 nodes/wave, 4 waves/block -> 8 nodes/block.
    const int blocks1 = (n_nodes + 7) / 8;
    edgeprompt_proj<<<blocks1, BLOCK, 0, stream>>>(x, W, proj, n_nodes);

    // K2: 4 edges/thread.
    const int blocks2 = ((n_edges + 3) / 4 + BLOCK - 1) / BLOCK;
    edgeprompt_edges<<<blocks2, BLOCK, 0, stream>>>(edge_index, edge_weight, proj, b,
                                                    out, n_edges, n_nodes);
}

// Round 5
// 16.706 us; speedup vs baseline: 5.7078x; 1.0334x over previous
//
#include <hip/hip_runtime.h>
#include <hip/hip_bf16.h>

// EdgePrompt: out[e] = edge_weight[e] * sigmoid( x[src[e]]·W[:d] + x[dst[e]]·W[d:] + b )
// Two launches (cooperative grid.sync was a 4.6x regression — R2 post-mortem):
//   K1: proj_src[n] = x[n]·W[:d], proj_dst[n] = x[n]·W[d:]  (into d_ws)
//       4 nodes/wave: 16 lanes/node, 32 B/lane (2x float4), 4-level butterfly.
//   K2: per-edge gather + sigmoid + scale, 4 edges/thread, non-temporal streams.
// NOTE: __builtin_nontemporal_* requires clang ext_vector_type, not
// HIP_vector_type (R4 compile fail) — use i32x4/f32x4 typedefs.

#define IN_DIM 128
#define BLOCK 256
#define K1_BLOCKS 2048   // 8 blocks/CU on 256 CUs — all co-resident, grid-stride

typedef int   i32x4 __attribute__((ext_vector_type(4)));
typedef float f32x4 __attribute__((ext_vector_type(4)));

__global__ void __launch_bounds__(BLOCK)
edgeprompt_proj(const float* __restrict__ x,
                const float* __restrict__ W,
                float* __restrict__ proj,   // [2*n_nodes]: [0,N)=src-proj, [N,2N)=dst-proj
                int n_nodes) {
    const int lane = threadIdx.x & 63;
    const int g    = lane >> 4;        // node slot within the wave (0..3)
    const int sg   = lane & 15;        // sub-lane within the 16-lane group
    const int wave = (blockIdx.x * blockDim.x + threadIdx.x) >> 6;
    const int nwaves = (gridDim.x * blockDim.x) >> 6;

    // W is 1 KB, node-invariant: hoist the per-lane fragments (L1-resident).
    const f32x4 ws0 = *reinterpret_cast<const f32x4*>(&W[sg * 4]);
    const f32x4 ws1 = *reinterpret_cast<const f32x4*>(&W[64 + sg * 4]);
    const f32x4 wd0 = *reinterpret_cast<const f32x4*>(&W[IN_DIM + sg * 4]);
    const f32x4 wd1 = *reinterpret_cast<const f32x4*>(&W[IN_DIM + 64 + sg * 4]);

    const int nquads = (n_nodes + 3) >> 2;
    for (int qn = wave; qn < nquads; qn += nwaves) {
        const int n = qn * 4 + g;
        float ps = 0.f, pd = 0.f;
        if (n < n_nodes) {
            const float* xr = &x[(size_t)n * IN_DIM + sg * 4];
            const f32x4 x0 = *reinterpret_cast<const f32x4*>(xr);
            const f32x4 x1 = *reinterpret_cast<const f32x4*>(xr + 64);
            ps = x0.x * ws0.x + x0.y * ws0.y + x0.z * ws0.z + x0.w * ws0.w
               + x1.x * ws1.x + x1.y * ws1.y + x1.z * ws1.z + x1.w * ws1.w;
            pd = x0.x * wd0.x + x0.y * wd0.y + x0.z * wd0.z + x0.w * wd0.w
               + x1.x * wd1.x + x1.y * wd1.y + x1.z * wd1.z + x1.w * wd1.w;
        }
        // 16-lane butterfly (xor offsets <16 never cross the group boundary)
        #pragma unroll
        for (int off = 8; off > 0; off >>= 1) {
            ps += __shfl_xor(ps, off);
            pd += __shfl_xor(pd, off);
        }
        if (sg == 0 && n < n_nodes) {
            proj[n] = ps;
            proj[n_nodes + n] = pd;
        }
    }
}

// K2: 4 edges/thread. Streamed arrays (idx/ew/out) use non-temporal accesses
// so the 400 KB proj gather tables stay L2-resident.
__global__ void __launch_bounds__(BLOCK)
edgeprompt_edges(const int* __restrict__ edge_index,   // [2*E]: [0,E)=src, [E,2E)=dst
                 const float* __restrict__ edge_weight,
                 const float* __restrict__ proj,       // [2*n_nodes]
                 const float* __restrict__ bias_p,
                 float* __restrict__ out,
                 int n_edges, int n_nodes) {
    const int tid = blockIdx.x * blockDim.x + threadIdx.x;
    const float bias = bias_p[0];
    const float* __restrict__ proj_d = proj + n_nodes;

    const int nquads = n_edges >> 2;
    if (tid < nquads) {
        const i32x4 s4 = __builtin_nontemporal_load(
                             reinterpret_cast<const i32x4*>(&edge_index[tid * 4]));
        const i32x4 d4 = __builtin_nontemporal_load(
                             reinterpret_cast<const i32x4*>(&edge_index[n_edges + tid * 4]));
        const f32x4 w4 = __builtin_nontemporal_load(
                             reinterpret_cast<const f32x4*>(&edge_weight[tid * 4]));
        f32x4 o;
        o.x = w4.x / (1.0f + __expf(-(proj[s4.x] + proj_d[d4.x] + bias)));
        o.y = w4.y / (1.0f + __expf(-(proj[s4.y] + proj_d[d4.y] + bias)));
        o.z = w4.z / (1.0f + __expf(-(proj[s4.z] + proj_d[d4.z] + bias)));
        o.w = w4.w / (1.0f + __expf(-(proj[s4.w] + proj_d[d4.w] + bias)));
        __builtin_nontemporal_store(o, reinterpret_cast<f32x4*>(&out[tid * 4]));
    }
    // tail (n_edges % 4), handled by the first few threads
    const int e = (nquads << 2) + tid;
    if (e < n_edges) {
        const int s = edge_index[e];
        const int d = edge_index[n_edges + e];
        out[e] = edge_weight[e] / (1.0f + __expf(-(proj[s] + proj_d[d] + bias)));
    }
}

extern "C" void kernel_launch(void* const* d_in, const int* in_sizes, int n_in,
                              void* d_out, int out_size, void* d_ws, size_t ws_size,
                              hipStream_t stream) {
    // setup_inputs() order: x, edge_index, edge_weight, W, b
    const float* x           = (const float*)d_in[0];
    const int*   edge_index  = (const int*)d_in[1];
    const float* edge_weight = (const float*)d_in[2];
    const float* W           = (const float*)d_in[3];
    const float* b           = (const float*)d_in[4];
    float* out = (float*)d_out;

    const int n_nodes = in_sizes[0] / IN_DIM;   // 50000
    const int n_edges = in_sizes[2];            // 500000
    float* proj = (float*)d_ws;                 // 2*n_nodes floats = 400 KB

    // K1: grid-stride, 16 nodes/block/iter.
    const int nquads1 = (n_nodes + 3) / 4;
    const int blocks1 = min(K1_BLOCKS, (nquads1 + 3) / 4);
    edgeprompt_proj<<<blocks1, BLOCK, 0, stream>>>(x, W, proj, n_nodes);

    // K2: 4 edges/thread, one-shot.
    const int blocks2 = ((n_edges + 3) / 4 + BLOCK - 1) / BLOCK;
    edgeprompt_edges<<<blocks2, BLOCK, 0, stream>>>(edge_index, edge_weight, proj, b,
                                                    out, n_edges, n_nodes);
}